// Round 10
// baseline (387.573 us; speedup 1.0000x reference)
//
#include <hip/hip_runtime.h>
#include <hip/hip_bf16.h>
#include <stdint.h>

// ---------------------------------------------------------------------------
// SGI grid-GCN head on MI355X.  Round 14 — full-balance instrumentation:
//  - The ledger doesn't close: gemm_h 100 + prep ~62 + modeled small kernels
//    ~100 = ~262 vs 370 total, residue ~105us stable across ALL configs.
//    Either gemm_o/gemm2/stencil2 are ~2x their rooflines, or ~100us is
//    fixed overhead.  Opposite remedies -> measure, don't guess.
//  - prep split into 3 dispatches (x bb01 / x bb23 / weights), gemm_h into
//    3 n-slices (512 blocks, r6-proven packing-neutral).  Every known kernel
//    now <= ~35us, so the rocprof top-5 MUST surface the slowest of
//    {gemm_o, gemm2, stencil2} with counters.
//  - Pre-committed: round 15 attacks whatever tops the table; if only
//    gemm_h-thirds/prep show (~35), residue = overhead -> merge dispatches.
//  9 dispatches: prep x3, gemm_h x3, gemm_o, gemm2, stencil2.
// ---------------------------------------------------------------------------

typedef __bf16 bf16;
typedef float f32x4 __attribute__((ext_vector_type(4)));
typedef bf16 bf16x8 __attribute__((ext_vector_type(8)));

#define NB 4
#define NN 4096
#define CIN 1536
#define HIDF 1536
#define OUTF 512

// rsqrt(deg) for deg = 1+(gx>0)+(gx<63)+(gy>0)+(gy<63) in {3,4,5}:
// select from constants (exact factorization of rsqrtf(deg_i*deg_j)).
__device__ __forceinline__ float rs_of(int gx, int gy) {
  const int d = (gx > 0) + (gx < 63) + (gy > 0) + (gy < 63);  // deg-1 in 2..4
  return d == 2 ? 0.57735027f : (d == 3 ? 0.5f : 0.44721360f);
}

// ------------------------------- prep ---------------------------------------
// x-path: block = 256 threads, one 64(c) x 4-yrow (256 n) band, rows done
// sequentially with register-carried halo.  Weight path unchanged.
// Launched in 3 slices via `base`: [0,768) x bb01, [768,1536) x bb23,
// [1536,2496) weights.
#define XBLK 1536
#define W1BLK 576
#define W2BLK 192

__global__ __launch_bounds__(256) void prep(
    const float* __restrict__ x, const float* __restrict__ W1,
    const float* __restrict__ W2, const float* __restrict__ Wl,
    bf16* __restrict__ xt, bf16* __restrict__ xa, bf16* __restrict__ w1t,
    bf16* __restrict__ w2t, bf16* __restrict__ wlt, int base) {
  __shared__ float vt[64 * 64];
  __shared__ float at[64 * 64];
  const int B = blockIdx.x + base, t = threadIdx.x;
  const int tx = t & 15, ty = t >> 4;      // load phase: n4 = tx*4, c = ty*4+cc
  const int lane = t & 63, w = t >> 6;     // store phase
  const int u = lane & 7, n3 = lane >> 3;  // c-slot / n-subrow

  if (B < XBLK) {
    // XCD k owns ybands {2k, 2k+1}: halo rows stay XCD-local.
    const int yb = (B & 7) * 2 + ((B >> 3) & 1);  // 0..15
    const int rest = B >> 4;                      // 0..95
    const int ct = rest % 24, bb = rest / 24;
    const int c0 = ct * 64;
    const float* xb = x + (long)bb * CIN * NN;
    const float* rowb = xb + (long)(c0 + ty * 4) * NN + tx * 4;
    bf16* xtb = xt + (long)bb * NN * CIN;
    bf16* xab = xa + (long)bb * NN * CIN;

    // ---- prologue: rows gy0-1 (up), gy0 (cur), gy0+1 (dn) ----
    f32x4 vup[4], vcur[4], vdn[4];
    const int gy0 = yb * 4;
    if (gy0 > 0) {
#pragma unroll
      for (int cc = 0; cc < 4; cc++)
        vup[cc] = *(const f32x4*)(rowb + (long)cc * NN + (long)(gy0 - 1) * 64);
    } else {
#pragma unroll
      for (int cc = 0; cc < 4; cc++) vup[cc] = {0.f, 0.f, 0.f, 0.f};
    }
#pragma unroll
    for (int cc = 0; cc < 4; cc++)
      vcur[cc] = *(const f32x4*)(rowb + (long)cc * NN + (long)gy0 * 64);
#pragma unroll
    for (int cc = 0; cc < 4; cc++)
      vdn[cc] = *(const f32x4*)(rowb + (long)cc * NN + (long)(gy0 + 1) * 64);

#pragma unroll
    for (int s = 0; s < 4; s++) {
      const int gy = yb * 4 + s;
      const int n0 = gy * 64;
      // halo via shuffle (lane-1/lane+1 share ty); tx==0/15 garbage is
      // masked by the gx>0 / gx<63 predicates below.
      float lf[4], rt[4];
#pragma unroll
      for (int cc = 0; cc < 4; cc++) {
        lf[cc] = __shfl_up(vcur[cc][3], 1);
        rt[cc] = __shfl_down(vcur[cc][0], 1);
      }
#pragma unroll
      for (int cc = 0; cc < 4; cc++) {
        const int cl = ty * 4 + cc;
        const int nb = tx * 4;
        f32x4 a;
#pragma unroll
        for (int i = 0; i < 4; i++) {
          const int gx = nb + i;
          const float rs_s = rs_of(gx, gy);
          const float lv = (i == 0) ? lf[cc] : vcur[cc][i - 1];
          const float rv = (i == 3) ? rt[cc] : vcur[cc][i + 1];
          float sum = vcur[cc][i] * rs_s;  // self: *rs_s below -> v/deg
          if (gx > 0) sum += lv * rs_of(gx - 1, gy);
          if (gx < 63) sum += rv * rs_of(gx + 1, gy);
          if (gy > 0) sum += vup[cc][i] * rs_of(gx, gy - 1);
          if (gy < 63) sum += vdn[cc][i] * rs_of(gx, gy + 1);
          a[i] = rs_s * sum;
        }
        const int chunk = tx ^ (2 * ((cl >> 3) & 7));
        *(f32x4*)&vt[cl * 64 + chunk * 4] = vcur[cc];
        *(f32x4*)&at[cl * 64 + chunk * 4] = a;
      }
      // prefetch next row's dn (row gy+2) BEFORE the barrier.
      f32x4 vnext[4];
      if (s < 3) {
        const int gn = gy + 2;
        if (gn <= 63) {
#pragma unroll
          for (int cc = 0; cc < 4; cc++)
            vnext[cc] =
                *(const f32x4*)(rowb + (long)cc * NN + (long)gn * 64);
        } else {
#pragma unroll
          for (int cc = 0; cc < 4; cc++) vnext[cc] = {0.f, 0.f, 0.f, 0.f};
        }
      }
      __syncthreads();
      // ---- transpose store ----
#pragma unroll
      for (int q = 0; q < 4; q++) {
        const int j = q * 4 + w;            // 0..15
        const int arr = j & 1, r2 = j >> 1; // array / n-row group
        const int nl = n3 + 8 * r2;
        const float* sp = arr ? at : vt;
        bf16x8 o;
#pragma unroll
        for (int jj = 0; jj < 8; jj++) {
          const int cl = u * 8 + jj;
          const int col = nl ^ (8 * ((cl >> 3) & 7));
          o[jj] = (bf16)sp[cl * 64 + col];
        }
        bf16* outp = arr ? xab : xtb;
        *(bf16x8*)&outp[(long)(n0 + nl) * CIN + c0 + u * 8] = o;
      }
      if (s < 3) {
        __syncthreads();  // LDS reads done before next row overwrites
#pragma unroll
        for (int cc = 0; cc < 4; cc++) {
          vup[cc] = vcur[cc];
          vcur[cc] = vdn[cc];
          vdn[cc] = vnext[cc];
        }
      }
    }
  } else {
    // ---- weight transpose: src [K][F] fp32 -> dst [F][K] bf16 ----
    int B2 = B - XBLK;
    const float* srcp;
    bf16* dstp;
    int Fdim, Kd, nt, ct;
    if (B2 < W1BLK) {
      nt = B2 / 24; ct = B2 % 24; srcp = W1; dstp = w1t; Fdim = HIDF; Kd = CIN;
    } else if (B2 < W1BLK + W2BLK) {
      const int l = B2 - W1BLK;
      nt = l / 24; ct = l % 24; srcp = W2; dstp = w2t; Fdim = OUTF; Kd = HIDF;
    } else {
      const int l = B2 - W1BLK - W2BLK;
      nt = l / 24; ct = l % 24; srcp = Wl; dstp = wlt; Fdim = OUTF; Kd = CIN;
    }
    const int n0 = nt * 64, c0 = ct * 64;
#pragma unroll
    for (int cc = 0; cc < 4; cc++) {
      const int cl = ty * 4 + cc;
      const float* row = srcp + (long)(c0 + cl) * Fdim + n0;
      f32x4 v = *(const f32x4*)(row + tx * 4);
      const int chunk = tx ^ (2 * ((cl >> 3) & 7));
      *(f32x4*)&vt[cl * 64 + chunk * 4] = v;
    }
    __syncthreads();
#pragma unroll
    for (int q = 0; q < 2; q++) {
      const int r = q * 4 + w;           // 0..7
      const int nl = n3 + 8 * r;
      bf16x8 o;
#pragma unroll
      for (int jj = 0; jj < 8; jj++) {
        const int cl = u * 8 + jj;
        const int col = nl ^ (8 * ((cl >> 3) & 7));
        o[jj] = (bf16)vt[cl * 64 + col];
      }
      *(bf16x8*)&dstp[(long)(n0 + nl) * Kd + c0 + u * 8] = o;
    }
  }
}

// ------------------------------- GEMM core ---------------------------------
__device__ __forceinline__ void async_copy16(const void* g, void* l) {
  __builtin_amdgcn_global_load_lds(
      (const __attribute__((address_space(1))) void*)g,
      (__attribute__((address_space(3))) void*)l, 16, 0, 0);
}

struct GemmCtx {
  f32x4 acc[4][4];
  int wave, lane, wm, wn, quad, l15;
};

__device__ __forceinline__ void gemm_init(GemmCtx& cx, int t) {
  cx.wave = t >> 6;
  cx.lane = t & 63;
  cx.wm = (cx.wave & 1) * 64;
  cx.wn = (cx.wave >> 1) * 64;
  cx.quad = cx.lane >> 4;
  cx.l15 = cx.lane & 15;
#pragma unroll
  for (int i = 0; i < 4; i++)
#pragma unroll
    for (int j = 0; j < 4; j++) cx.acc[i][j] = {0.f, 0.f, 0.f, 0.f};
}

// 2-phase double-buffered K-loop (proven r7: gemm_h 120.5 -> 96.6us).
template <int K>
__device__ __forceinline__ void gemm_kloop(GemmCtx& cx, const bf16* Ab,
                                           const bf16* Bb, bf16* As,
                                           bf16* Bs) {
  const int r = cx.lane >> 3, c8 = cx.lane & 7;
  const int fchunk = c8 ^ r;
  constexpr int NT = K / 64;
  // prologue: stage tile 0 into buffer 0
#pragma unroll
  for (int i = 0; i < 4; i++) {
    const int row = i * 32 + cx.wave * 8;
    async_copy16(Ab + (long)(row + r) * K + fchunk * 8, &As[row * 64]);
    async_copy16(Bb + (long)(row + r) * K + fchunk * 8, &Bs[row * 64]);
  }
  __syncthreads();
#pragma unroll 2
  for (int t = 0; t < NT; ++t) {
    const int cur = (t & 1) * (128 * 64);
    const int nxt = cur ^ (128 * 64);
    // last iter re-stages its own tile (L2-hot) to keep flow uniform
    const int ktn = ((t + 1 < NT) ? t + 1 : t) * 64;
#pragma unroll
    for (int i = 0; i < 4; i++) {
      const int row = i * 32 + cx.wave * 8;
      async_copy16(Ab + (long)(row + r) * K + ktn + fchunk * 8,
                   &As[nxt + row * 64]);
      async_copy16(Bb + (long)(row + r) * K + ktn + fchunk * 8,
                   &Bs[nxt + row * 64]);
    }
#pragma unroll
    for (int kk = 0; kk < 2; kk++) {
      const int q = kk * 4 + cx.quad;
      bf16x8 af[4], bfv[4];
#pragma unroll
      for (int mr = 0; mr < 4; mr++) {
        const int m = cx.wm + mr * 16 + cx.l15;
        af[mr] = *(const bf16x8*)&As[cur + m * 64 + (q ^ (m & 7)) * 8];
      }
#pragma unroll
      for (int nc = 0; nc < 4; nc++) {
        const int n = cx.wn + nc * 16 + cx.l15;
        bfv[nc] = *(const bf16x8*)&Bs[cur + n * 64 + (q ^ (n & 7)) * 8];
      }
#pragma unroll
      for (int mr = 0; mr < 4; mr++)
#pragma unroll
        for (int nc = 0; nc < 4; nc++)
          cx.acc[mr][nc] = __builtin_amdgcn_mfma_f32_16x16x32_bf16(
              af[mr], bfv[nc], cx.acc[mr][nc], 0, 0, 0);
    }
    __syncthreads();
  }
}

// h = bf16( relu(xa @ w1t^T + b1) + xt )   [B][NN][HIDF], one n-third.
__global__ __launch_bounds__(256) void gemm_h(
    const bf16* __restrict__ xa, const bf16* __restrict__ w1t,
    const bf16* __restrict__ xt, bf16* __restrict__ h,
    const float* __restrict__ b1, int nbase) {
  __shared__ bf16 As[2 * 128 * 64];
  __shared__ bf16 Bs[2 * 128 * 64];
  GemmCtx cx;
  gemm_init(cx, threadIdx.x);
  const int m0 = blockIdx.x * 128, n0 = nbase + blockIdx.y * 128;
  const int z = blockIdx.z;
  gemm_kloop<CIN>(cx, xa + (long)z * NN * CIN + (long)m0 * CIN,
                  w1t + (long)n0 * CIN, As, Bs);
  const bf16* Xb = xt + (long)z * NN * HIDF;
  bf16* Cb = h + (long)z * NN * HIDF;
#pragma unroll
  for (int mr = 0; mr < 4; mr++)
#pragma unroll
    for (int nc = 0; nc < 4; nc++) {
      const int gn = n0 + cx.wn + nc * 16 + cx.l15;
      const float bv = b1[gn];
#pragma unroll
      for (int j = 0; j < 4; j++) {
        const int gm = m0 + cx.wm + mr * 16 + cx.quad * 4 + j;
        float v = cx.acc[mr][nc][j] + bv;
        v = v > 0.f ? v : 0.f;
        Cb[(long)gm * HIDF + gn] = (bf16)(v + (float)Xb[(long)gm * HIDF + gn]);
      }
    }
}

// fp32-out GEMM (gemm_o with bias, gemm2 without).  K = 1536 both.
template <bool ADD_BIAS>
__global__ __launch_bounds__(256) void gemm_f32(
    const bf16* __restrict__ A, const bf16* __restrict__ Bw,
    float* __restrict__ C, const float* __restrict__ bias) {
  __shared__ bf16 As[2 * 128 * 64];
  __shared__ bf16 Bs[2 * 128 * 64];
  GemmCtx cx;
  gemm_init(cx, threadIdx.x);
  const int m0 = blockIdx.x * 128, n0 = blockIdx.y * 128, z = blockIdx.z;
  gemm_kloop<CIN>(cx, A + (long)z * NN * CIN + (long)m0 * CIN,
                  Bw + (long)n0 * CIN, As, Bs);
  float* Cb = C + (long)z * NN * OUTF;
#pragma unroll
  for (int mr = 0; mr < 4; mr++)
#pragma unroll
    for (int nc = 0; nc < 4; nc++) {
      const int gn = n0 + cx.wn + nc * 16 + cx.l15;
      float bv = 0.f;
      if (ADD_BIAS) bv = bias[gn];
#pragma unroll
      for (int j = 0; j < 4; j++) {
        const int gm = m0 + cx.wm + mr * 16 + cx.quad * 4 + j;
        Cb[(long)gm * OUTF + gn] = cx.acc[mr][nc][j] + bv;
      }
    }
}

// ------------------------------- stencil2 ----------------------------------
// out[b][f][n] = (Agg(G2)[n][f] + b2[f]) * Origin[n][f]; transpose via LDS.
// Factored norm: agg = rs_n*(g*rs_n + sum u*rs_nbr).
__global__ __launch_bounds__(256) void stencil2(
    const float* __restrict__ G2, const float* __restrict__ Orig,
    const float* __restrict__ b2, float* __restrict__ out) {
  __shared__ float tile[16][516];
  const int blk = blockIdx.x;                        // 256 strips
  const int s = ((blk & 7) << 5) + (blk >> 3);       // XCD-contiguous
  const int n0 = s * 16, b = blockIdx.y;
  const int t = threadIdx.x;
  const int fq = t & 127, nl = t >> 7;
  const int f = fq * 4;
  const f32x4 bv = *(const f32x4*)(b2 + f);
#pragma unroll
  for (int p = 0; p < 8; p++) {
    const int nLoc = p * 2 + nl;
    const int n = n0 + nLoc;
    const int gx = n & 63, gy = n >> 6;
    const float rs_n = rs_of(gx, gy);
    const long rb = ((long)b * NN + n) * (long)OUTF + f;
    f32x4 g = *(const f32x4*)(G2 + rb);
    f32x4 a;
#pragma unroll
    for (int i = 0; i < 4; i++) a[i] = g[i] * rs_n;  // self term
    if (gx > 0) {
      const float w = rs_of(gx - 1, gy);
      f32x4 u = *(const f32x4*)(G2 + rb - OUTF);
#pragma unroll
      for (int i = 0; i < 4; i++) a[i] += u[i] * w;
    }
    if (gx < 63) {
      const float w = rs_of(gx + 1, gy);
      f32x4 u = *(const f32x4*)(G2 + rb + OUTF);
#pragma unroll
      for (int i = 0; i < 4; i++) a[i] += u[i] * w;
    }
    if (gy > 0) {
      const float w = rs_of(gx, gy - 1);
      f32x4 u = *(const f32x4*)(G2 + rb - 64L * OUTF);
#pragma unroll
      for (int i = 0; i < 4; i++) a[i] += u[i] * w;
    }
    if (gy < 63) {
      const float w = rs_of(gx, gy + 1);
      f32x4 u = *(const f32x4*)(G2 + rb + 64L * OUTF);
#pragma unroll
      for (int i = 0; i < 4; i++) a[i] += u[i] * w;
    }
    f32x4 og = *(const f32x4*)(Orig + rb);
    f32x4 res;
#pragma unroll
    for (int i = 0; i < 4; i++) res[i] = (a[i] * rs_n + bv[i]) * og[i];
    *(f32x4*)&tile[nLoc][f] = res;  // ds_write_b128 (row stride 16B-aligned)
  }
  __syncthreads();
  // phase 2: 4 lanes x f32x4 per ff-row (vector stores, 2-way bank alias).
  const int j = t & 3, fr = t >> 2;  // n4 = j*4 ; fr = 0..63
#pragma unroll
  for (int q = 0; q < 8; q++) {
    const int ff = q * 64 + fr;
    f32x4 v;
#pragma unroll
    for (int k = 0; k < 4; k++) v[k] = tile[j * 4 + k][ff];
    *(f32x4*)&out[((long)b * OUTF + ff) * (long)NN + n0 + j * 4] = v;
  }
}

// ------------------------------- launcher ----------------------------------
extern "C" void kernel_launch(void* const* d_in, const int* in_sizes, int n_in,
                              void* d_out, int out_size, void* d_ws,
                              size_t ws_size, hipStream_t stream) {
  const float* x = (const float*)d_in[0];
  const float* W1 = (const float*)d_in[1];
  const float* b1 = (const float*)d_in[2];
  const float* W2 = (const float*)d_in[3];
  const float* b2 = (const float*)d_in[4];
  const float* Wl = (const float*)d_in[5];
  const float* bl = (const float*)d_in[6];
  float* out = (float*)d_out;

  uint8_t* ws = (uint8_t*)d_ws;
  size_t off = 0;
  auto alloc = [&](size_t bytes) -> void* {
    void* p = ws + off;
    off += (bytes + 255) & ~(size_t)255;
    return p;
  };
  // Lifetimes: xt [prep..gemm_o], xa [prep..gemm_h], h [gemm_h..gemm2],
  //            origin [gemm_o..stencil2] (aliases xa), g2 [gemm2..stencil2]
  //            (aliases xt).
  bf16* xt = (bf16*)alloc((size_t)NB * NN * CIN * 2);   // 50.3 MB
  bf16* xa = (bf16*)alloc((size_t)NB * NN * CIN * 2);   // 50.3 MB
  bf16* hb = (bf16*)alloc((size_t)NB * NN * HIDF * 2);  // 50.3 MB
  bf16* w1t = (bf16*)alloc((size_t)HIDF * CIN * 2);     // 4.7 MB
  bf16* w2t = (bf16*)alloc((size_t)OUTF * HIDF * 2);    // 1.6 MB
  bf16* wlt = (bf16*)alloc((size_t)OUTF * CIN * 2);     // 1.6 MB (~159 MB)
  float* origin = (float*)xa;
  float* g2 = (float*)xt;

  // prep in 3 slices: x bb01 (768 = one full round @3/CU), x bb23 (768),
  // weights (960).  Weight slice precedes gemm_h in stream order.
  prep<<<768, 256, 0, stream>>>(x, W1, W2, Wl, xt, xa, w1t, w2t, wlt, 0);
  prep<<<768, 256, 0, stream>>>(x, W1, W2, Wl, xt, xa, w1t, w2t, wlt, 768);
  prep<<<960, 256, 0, stream>>>(x, W1, W2, Wl, xt, xa, w1t, w2t, wlt, 1536);
  // h = relu(xa @ W1 + b1) + xt  -- three 512-block n-slices (r6-proven
  // packing-neutral; drops visibility threshold to ~35us).
  gemm_h<<<dim3(NN / 128, 4, NB), 256, 0, stream>>>(xa, w1t, xt, hb, b1, 0);
  gemm_h<<<dim3(NN / 128, 4, NB), 256, 0, stream>>>(xa, w1t, xt, hb, b1, 512);
  gemm_h<<<dim3(NN / 128, 4, NB), 256, 0, stream>>>(xa, w1t, xt, hb, b1, 1024);
  // origin = xt @ Wl + bl  (overwrites xa slot — xa dead after gemm_h)
  gemm_f32<true><<<dim3(NN / 128, OUTF / 128, NB), 256, 0, stream>>>(
      xt, wlt, origin, bl);
  // g2 = h @ W2  (overwrites xt slot — xt dead after gemm_o)
  gemm_f32<false><<<dim3(NN / 128, OUTF / 128, NB), 256, 0, stream>>>(
      hb, w2t, g2, nullptr);
  // out = (Agg(g2)+b2) * origin, transposed to [B][OUT][N]
  stencil2<<<dim3(256, NB), 256, 0, stream>>>(g2, origin, b2, out);
}

// Round 11
// 360.623 us; speedup vs baseline: 1.0747x; 1.0747x over previous
//
#include <hip/hip_runtime.h>
#include <hip/hip_bf16.h>
#include <stdint.h>

// ---------------------------------------------------------------------------
// SGI grid-GCN head on MI355X.  Round 15:
//  - r14 finding: the ~105us residue is mostly a 384MiB harness workspace
//    re-poison fill (60.7us @ 6.7TB/s, HBM-roofline, not ours).  Ledger
//    closes: kernels ~250 + fill ~60 + gaps.  Only lever = kernel sum.
//  - Instrumentation splits REVERTED (5 dispatches).
//  - gemm_kloop: counted-vmcnt 2-stage pipeline (T4) replaces the
//    __syncthreads vmcnt(0) drain.  Stage tiles 0,1 up front; iter t:
//    vmcnt(8) [tile t landed, t+1 in flight] -> s_barrier -> MFMA ->
//    lgkmcnt(0) -> s_barrier -> stage tile t+2 into freed buffer.
//    Per-tile flight = full iteration (~2x previous).  Explicit vmcnt(0)
//    after the loop (orphaned global_load_lds must not land in a
//    successor block's LDS).  sched_barrier(0) fences per rule #18.
//  5 dispatches: prep, gemm_h, gemm_o, gemm2, stencil2.
// ---------------------------------------------------------------------------

typedef __bf16 bf16;
typedef float f32x4 __attribute__((ext_vector_type(4)));
typedef bf16 bf16x8 __attribute__((ext_vector_type(8)));

#define NB 4
#define NN 4096
#define CIN 1536
#define HIDF 1536
#define OUTF 512

// rsqrt(deg) for deg = 1+(gx>0)+(gx<63)+(gy>0)+(gy<63) in {3,4,5}:
// select from constants (exact factorization of rsqrtf(deg_i*deg_j)).
__device__ __forceinline__ float rs_of(int gx, int gy) {
  const int d = (gx > 0) + (gx < 63) + (gy > 0) + (gy < 63);  // deg-1 in 2..4
  return d == 2 ? 0.57735027f : (d == 3 ? 0.5f : 0.44721360f);
}

// ------------------------------- prep ---------------------------------------
// x-path: block = 256 threads, one 64(c) x 4-yrow (256 n) band, rows done
// sequentially with register-carried halo.  Weight path unchanged.
#define XBLK 1536
#define W1BLK 576
#define W2BLK 192

__global__ __launch_bounds__(256) void prep(
    const float* __restrict__ x, const float* __restrict__ W1,
    const float* __restrict__ W2, const float* __restrict__ Wl,
    bf16* __restrict__ xt, bf16* __restrict__ xa, bf16* __restrict__ w1t,
    bf16* __restrict__ w2t, bf16* __restrict__ wlt) {
  __shared__ float vt[64 * 64];
  __shared__ float at[64 * 64];
  const int B = blockIdx.x, t = threadIdx.x;
  const int tx = t & 15, ty = t >> 4;      // load phase: n4 = tx*4, c = ty*4+cc
  const int lane = t & 63, w = t >> 6;     // store phase
  const int u = lane & 7, n3 = lane >> 3;  // c-slot / n-subrow

  if (B < XBLK) {
    // XCD k owns ybands {2k, 2k+1}: halo rows stay XCD-local.
    const int yb = (B & 7) * 2 + ((B >> 3) & 1);  // 0..15
    const int rest = B >> 4;                      // 0..95
    const int ct = rest % 24, bb = rest / 24;
    const int c0 = ct * 64;
    const float* xb = x + (long)bb * CIN * NN;
    const float* rowb = xb + (long)(c0 + ty * 4) * NN + tx * 4;
    bf16* xtb = xt + (long)bb * NN * CIN;
    bf16* xab = xa + (long)bb * NN * CIN;

    // ---- prologue: rows gy0-1 (up), gy0 (cur), gy0+1 (dn) ----
    f32x4 vup[4], vcur[4], vdn[4];
    const int gy0 = yb * 4;
    if (gy0 > 0) {
#pragma unroll
      for (int cc = 0; cc < 4; cc++)
        vup[cc] = *(const f32x4*)(rowb + (long)cc * NN + (long)(gy0 - 1) * 64);
    } else {
#pragma unroll
      for (int cc = 0; cc < 4; cc++) vup[cc] = {0.f, 0.f, 0.f, 0.f};
    }
#pragma unroll
    for (int cc = 0; cc < 4; cc++)
      vcur[cc] = *(const f32x4*)(rowb + (long)cc * NN + (long)gy0 * 64);
#pragma unroll
    for (int cc = 0; cc < 4; cc++)
      vdn[cc] = *(const f32x4*)(rowb + (long)cc * NN + (long)(gy0 + 1) * 64);

#pragma unroll
    for (int s = 0; s < 4; s++) {
      const int gy = yb * 4 + s;
      const int n0 = gy * 64;
      // halo via shuffle (lane-1/lane+1 share ty); tx==0/15 garbage is
      // masked by the gx>0 / gx<63 predicates below.
      float lf[4], rt[4];
#pragma unroll
      for (int cc = 0; cc < 4; cc++) {
        lf[cc] = __shfl_up(vcur[cc][3], 1);
        rt[cc] = __shfl_down(vcur[cc][0], 1);
      }
#pragma unroll
      for (int cc = 0; cc < 4; cc++) {
        const int cl = ty * 4 + cc;
        const int nb = tx * 4;
        f32x4 a;
#pragma unroll
        for (int i = 0; i < 4; i++) {
          const int gx = nb + i;
          const float rs_s = rs_of(gx, gy);
          const float lv = (i == 0) ? lf[cc] : vcur[cc][i - 1];
          const float rv = (i == 3) ? rt[cc] : vcur[cc][i + 1];
          float sum = vcur[cc][i] * rs_s;  // self: *rs_s below -> v/deg
          if (gx > 0) sum += lv * rs_of(gx - 1, gy);
          if (gx < 63) sum += rv * rs_of(gx + 1, gy);
          if (gy > 0) sum += vup[cc][i] * rs_of(gx, gy - 1);
          if (gy < 63) sum += vdn[cc][i] * rs_of(gx, gy + 1);
          a[i] = rs_s * sum;
        }
        const int chunk = tx ^ (2 * ((cl >> 3) & 7));
        *(f32x4*)&vt[cl * 64 + chunk * 4] = vcur[cc];
        *(f32x4*)&at[cl * 64 + chunk * 4] = a;
      }
      // prefetch next row's dn (row gy+2) BEFORE the barrier.
      f32x4 vnext[4];
      if (s < 3) {
        const int gn = gy + 2;
        if (gn <= 63) {
#pragma unroll
          for (int cc = 0; cc < 4; cc++)
            vnext[cc] =
                *(const f32x4*)(rowb + (long)cc * NN + (long)gn * 64);
        } else {
#pragma unroll
          for (int cc = 0; cc < 4; cc++) vnext[cc] = {0.f, 0.f, 0.f, 0.f};
        }
      }
      __syncthreads();
      // ---- transpose store ----
#pragma unroll
      for (int q = 0; q < 4; q++) {
        const int j = q * 4 + w;            // 0..15
        const int arr = j & 1, r2 = j >> 1; // array / n-row group
        const int nl = n3 + 8 * r2;
        const float* sp = arr ? at : vt;
        bf16x8 o;
#pragma unroll
        for (int jj = 0; jj < 8; jj++) {
          const int cl = u * 8 + jj;
          const int col = nl ^ (8 * ((cl >> 3) & 7));
          o[jj] = (bf16)sp[cl * 64 + col];
        }
        bf16* outp = arr ? xab : xtb;
        *(bf16x8*)&outp[(long)(n0 + nl) * CIN + c0 + u * 8] = o;
      }
      if (s < 3) {
        __syncthreads();  // LDS reads done before next row overwrites
#pragma unroll
        for (int cc = 0; cc < 4; cc++) {
          vup[cc] = vcur[cc];
          vcur[cc] = vdn[cc];
          vdn[cc] = vnext[cc];
        }
      }
    }
  } else {
    // ---- weight transpose: src [K][F] fp32 -> dst [F][K] bf16 ----
    int B2 = B - XBLK;
    const float* srcp;
    bf16* dstp;
    int Fdim, Kd, nt, ct;
    if (B2 < W1BLK) {
      nt = B2 / 24; ct = B2 % 24; srcp = W1; dstp = w1t; Fdim = HIDF; Kd = CIN;
    } else if (B2 < W1BLK + W2BLK) {
      const int l = B2 - W1BLK;
      nt = l / 24; ct = l % 24; srcp = W2; dstp = w2t; Fdim = OUTF; Kd = HIDF;
    } else {
      const int l = B2 - W1BLK - W2BLK;
      nt = l / 24; ct = l % 24; srcp = Wl; dstp = wlt; Fdim = OUTF; Kd = CIN;
    }
    const int n0 = nt * 64, c0 = ct * 64;
#pragma unroll
    for (int cc = 0; cc < 4; cc++) {
      const int cl = ty * 4 + cc;
      const float* row = srcp + (long)(c0 + cl) * Fdim + n0;
      f32x4 v = *(const f32x4*)(row + tx * 4);
      const int chunk = tx ^ (2 * ((cl >> 3) & 7));
      *(f32x4*)&vt[cl * 64 + chunk * 4] = v;
    }
    __syncthreads();
#pragma unroll
    for (int q = 0; q < 2; q++) {
      const int r = q * 4 + w;           // 0..7
      const int nl = n3 + 8 * r;
      bf16x8 o;
#pragma unroll
      for (int jj = 0; jj < 8; jj++) {
        const int cl = u * 8 + jj;
        const int col = nl ^ (8 * ((cl >> 3) & 7));
        o[jj] = (bf16)vt[cl * 64 + col];
      }
      *(bf16x8*)&dstp[(long)(n0 + nl) * Kd + c0 + u * 8] = o;
    }
  }
}

// ------------------------------- GEMM core ---------------------------------
__device__ __forceinline__ void async_copy16(const void* g, void* l) {
  __builtin_amdgcn_global_load_lds(
      (const __attribute__((address_space(1))) void*)g,
      (__attribute__((address_space(3))) void*)l, 16, 0, 0);
}

struct GemmCtx {
  f32x4 acc[4][4];
  int wave, lane, wm, wn, quad, l15;
};

__device__ __forceinline__ void gemm_init(GemmCtx& cx, int t) {
  cx.wave = t >> 6;
  cx.lane = t & 63;
  cx.wm = (cx.wave & 1) * 64;
  cx.wn = (cx.wave >> 1) * 64;
  cx.quad = cx.lane >> 4;
  cx.l15 = cx.lane & 15;
#pragma unroll
  for (int i = 0; i < 4; i++)
#pragma unroll
    for (int j = 0; j < 4; j++) cx.acc[i][j] = {0.f, 0.f, 0.f, 0.f};
}

#define TS (128 * 64)

// Counted-vmcnt 2-stage pipelined K-loop (T4).  Per-wave ledger: 8
// global_load_lds per K-tile.  Invariant at iter t entry: outstanding <= 16
// (tiles t, t+1); vmcnt(8) retires exactly tile t's 8 (oldest, FIFO).
// Raw s_barrier (no implicit vmcnt(0) drain) + sched_barrier(0) fences.
// Tail: clamped re-stage writes only dead buffers; final vmcnt(0) stops
// orphaned DMA from landing in a successor block's LDS.
template <int K>
__device__ __forceinline__ void gemm_kloop(GemmCtx& cx, const bf16* Ab,
                                           const bf16* Bb, bf16* As,
                                           bf16* Bs) {
  const int r = cx.lane >> 3, c8 = cx.lane & 7;
  const int fchunk = c8 ^ r;
  constexpr int NT = K / 64;
  static_assert(K >= 128, "pipeline needs >=2 K-tiles");
  // prologue: stage tile 0 -> buf0, tile 1 -> buf1  (8 loads each)
#pragma unroll
  for (int i = 0; i < 4; i++) {
    const int row = i * 32 + cx.wave * 8;
    async_copy16(Ab + (long)(row + r) * K + fchunk * 8, &As[row * 64]);
    async_copy16(Bb + (long)(row + r) * K + fchunk * 8, &Bs[row * 64]);
  }
#pragma unroll
  for (int i = 0; i < 4; i++) {
    const int row = i * 32 + cx.wave * 8;
    async_copy16(Ab + (long)(row + r) * K + 64 + fchunk * 8,
                 &As[TS + row * 64]);
    async_copy16(Bb + (long)(row + r) * K + 64 + fchunk * 8,
                 &Bs[TS + row * 64]);
  }
#pragma unroll 2
  for (int t = 0; t < NT; ++t) {
    const int cur = (t & 1) * TS;
    // tile t's loads are the oldest 8 of <=16 outstanding -> landed.
    asm volatile("s_waitcnt vmcnt(8)" ::: "memory");
    __builtin_amdgcn_s_barrier();
    __builtin_amdgcn_sched_barrier(0);
#pragma unroll
    for (int kk = 0; kk < 2; kk++) {
      const int q = kk * 4 + cx.quad;
      bf16x8 af[4], bfv[4];
#pragma unroll
      for (int mr = 0; mr < 4; mr++) {
        const int m = cx.wm + mr * 16 + cx.l15;
        af[mr] = *(const bf16x8*)&As[cur + m * 64 + (q ^ (m & 7)) * 8];
      }
#pragma unroll
      for (int nc = 0; nc < 4; nc++) {
        const int n = cx.wn + nc * 16 + cx.l15;
        bfv[nc] = *(const bf16x8*)&Bs[cur + n * 64 + (q ^ (n & 7)) * 8];
      }
#pragma unroll
      for (int mr = 0; mr < 4; mr++)
#pragma unroll
        for (int nc = 0; nc < 4; nc++)
          cx.acc[mr][nc] = __builtin_amdgcn_mfma_f32_16x16x32_bf16(
              af[mr], bfv[nc], cx.acc[mr][nc], 0, 0, 0);
    }
    // all my ds_reads of buf[cur] retired; then block-wide rendezvous
    // before anyone overwrites it.
    asm volatile("s_waitcnt lgkmcnt(0)" ::: "memory");
    __builtin_amdgcn_sched_barrier(0);
    __builtin_amdgcn_s_barrier();
    __builtin_amdgcn_sched_barrier(0);
    // stage tile t+2 into the just-freed buffer (clamped tail re-stage
    // targets a buffer that is never read again).
    const int ktn = (t + 2 < NT ? t + 2 : NT - 1) * 64;
#pragma unroll
    for (int i = 0; i < 4; i++) {
      const int row = i * 32 + cx.wave * 8;
      async_copy16(Ab + (long)(row + r) * K + ktn + fchunk * 8,
                   &As[cur + row * 64]);
      async_copy16(Bb + (long)(row + r) * K + ktn + fchunk * 8,
                   &Bs[cur + row * 64]);
    }
    __builtin_amdgcn_sched_barrier(0);
  }
  // drain orphaned DMA before this block's LDS can be reassigned.
  asm volatile("s_waitcnt vmcnt(0)" ::: "memory");
}

// h = bf16( relu(xa @ w1t^T + b1) + xt )   [B][NN][HIDF]
__global__ __launch_bounds__(256) void gemm_h(
    const bf16* __restrict__ xa, const bf16* __restrict__ w1t,
    const bf16* __restrict__ xt, bf16* __restrict__ h,
    const float* __restrict__ b1) {
  __shared__ bf16 As[2 * TS];
  __shared__ bf16 Bs[2 * TS];
  GemmCtx cx;
  gemm_init(cx, threadIdx.x);
  const int m0 = blockIdx.x * 128, n0 = blockIdx.y * 128, z = blockIdx.z;
  gemm_kloop<CIN>(cx, xa + (long)z * NN * CIN + (long)m0 * CIN,
                  w1t + (long)n0 * CIN, As, Bs);
  const bf16* Xb = xt + (long)z * NN * HIDF;
  bf16* Cb = h + (long)z * NN * HIDF;
#pragma unroll
  for (int mr = 0; mr < 4; mr++)
#pragma unroll
    for (int nc = 0; nc < 4; nc++) {
      const int gn = n0 + cx.wn + nc * 16 + cx.l15;
      const float bv = b1[gn];
#pragma unroll
      for (int j = 0; j < 4; j++) {
        const int gm = m0 + cx.wm + mr * 16 + cx.quad * 4 + j;
        float v = cx.acc[mr][nc][j] + bv;
        v = v > 0.f ? v : 0.f;
        Cb[(long)gm * HIDF + gn] = (bf16)(v + (float)Xb[(long)gm * HIDF + gn]);
      }
    }
}

// fp32-out GEMM (gemm_o with bias, gemm2 without).  K = 1536 both.
template <bool ADD_BIAS>
__global__ __launch_bounds__(256) void gemm_f32(
    const bf16* __restrict__ A, const bf16* __restrict__ Bw,
    float* __restrict__ C, const float* __restrict__ bias) {
  __shared__ bf16 As[2 * TS];
  __shared__ bf16 Bs[2 * TS];
  GemmCtx cx;
  gemm_init(cx, threadIdx.x);
  const int m0 = blockIdx.x * 128, n0 = blockIdx.y * 128, z = blockIdx.z;
  gemm_kloop<CIN>(cx, A + (long)z * NN * CIN + (long)m0 * CIN,
                  Bw + (long)n0 * CIN, As, Bs);
  float* Cb = C + (long)z * NN * OUTF;
#pragma unroll
  for (int mr = 0; mr < 4; mr++)
#pragma unroll
    for (int nc = 0; nc < 4; nc++) {
      const int gn = n0 + cx.wn + nc * 16 + cx.l15;
      float bv = 0.f;
      if (ADD_BIAS) bv = bias[gn];
#pragma unroll
      for (int j = 0; j < 4; j++) {
        const int gm = m0 + cx.wm + mr * 16 + cx.quad * 4 + j;
        Cb[(long)gm * OUTF + gn] = cx.acc[mr][nc][j] + bv;
      }
    }
}

// ------------------------------- stencil2 ----------------------------------
// out[b][f][n] = (Agg(G2)[n][f] + b2[f]) * Origin[n][f]; transpose via LDS.
// Factored norm: agg = rs_n*(g*rs_n + sum u*rs_nbr).
__global__ __launch_bounds__(256) void stencil2(
    const float* __restrict__ G2, const float* __restrict__ Orig,
    const float* __restrict__ b2, float* __restrict__ out) {
  __shared__ float tile[16][516];
  const int blk = blockIdx.x;                        // 256 strips
  const int s = ((blk & 7) << 5) + (blk >> 3);       // XCD-contiguous
  const int n0 = s * 16, b = blockIdx.y;
  const int t = threadIdx.x;
  const int fq = t & 127, nl = t >> 7;
  const int f = fq * 4;
  const f32x4 bv = *(const f32x4*)(b2 + f);
#pragma unroll
  for (int p = 0; p < 8; p++) {
    const int nLoc = p * 2 + nl;
    const int n = n0 + nLoc;
    const int gx = n & 63, gy = n >> 6;
    const float rs_n = rs_of(gx, gy);
    const long rb = ((long)b * NN + n) * (long)OUTF + f;
    f32x4 g = *(const f32x4*)(G2 + rb);
    f32x4 a;
#pragma unroll
    for (int i = 0; i < 4; i++) a[i] = g[i] * rs_n;  // self term
    if (gx > 0) {
      const float w = rs_of(gx - 1, gy);
      f32x4 u = *(const f32x4*)(G2 + rb - OUTF);
#pragma unroll
      for (int i = 0; i < 4; i++) a[i] += u[i] * w;
    }
    if (gx < 63) {
      const float w = rs_of(gx + 1, gy);
      f32x4 u = *(const f32x4*)(G2 + rb + OUTF);
#pragma unroll
      for (int i = 0; i < 4; i++) a[i] += u[i] * w;
    }
    if (gy > 0) {
      const float w = rs_of(gx, gy - 1);
      f32x4 u = *(const f32x4*)(G2 + rb - 64L * OUTF);
#pragma unroll
      for (int i = 0; i < 4; i++) a[i] += u[i] * w;
    }
    if (gy < 63) {
      const float w = rs_of(gx, gy + 1);
      f32x4 u = *(const f32x4*)(G2 + rb + 64L * OUTF);
#pragma unroll
      for (int i = 0; i < 4; i++) a[i] += u[i] * w;
    }
    f32x4 og = *(const f32x4*)(Orig + rb);
    f32x4 res;
#pragma unroll
    for (int i = 0; i < 4; i++) res[i] = (a[i] * rs_n + bv[i]) * og[i];
    *(f32x4*)&tile[nLoc][f] = res;  // ds_write_b128 (row stride 16B-aligned)
  }
  __syncthreads();
  // phase 2: 4 lanes x f32x4 per ff-row (vector stores, 2-way bank alias).
  const int j = t & 3, fr = t >> 2;  // n4 = j*4 ; fr = 0..63
#pragma unroll
  for (int q = 0; q < 8; q++) {
    const int ff = q * 64 + fr;
    f32x4 v;
#pragma unroll
    for (int k = 0; k < 4; k++) v[k] = tile[j * 4 + k][ff];
    *(f32x4*)&out[((long)b * OUTF + ff) * (long)NN + n0 + j * 4] = v;
  }
}

// ------------------------------- launcher ----------------------------------
extern "C" void kernel_launch(void* const* d_in, const int* in_sizes, int n_in,
                              void* d_out, int out_size, void* d_ws,
                              size_t ws_size, hipStream_t stream) {
  const float* x = (const float*)d_in[0];
  const float* W1 = (const float*)d_in[1];
  const float* b1 = (const float*)d_in[2];
  const float* W2 = (const float*)d_in[3];
  const float* b2 = (const float*)d_in[4];
  const float* Wl = (const float*)d_in[5];
  const float* bl = (const float*)d_in[6];
  float* out = (float*)d_out;

  uint8_t* ws = (uint8_t*)d_ws;
  size_t off = 0;
  auto alloc = [&](size_t bytes) -> void* {
    void* p = ws + off;
    off += (bytes + 255) & ~(size_t)255;
    return p;
  };
  // Lifetimes: xt [prep..gemm_o], xa [prep..gemm_h], h [gemm_h..gemm2],
  //            origin [gemm_o..stencil2] (aliases xa), g2 [gemm2..stencil2]
  //            (aliases xt).
  bf16* xt = (bf16*)alloc((size_t)NB * NN * CIN * 2);   // 50.3 MB
  bf16* xa = (bf16*)alloc((size_t)NB * NN * CIN * 2);   // 50.3 MB
  bf16* hb = (bf16*)alloc((size_t)NB * NN * HIDF * 2);  // 50.3 MB
  bf16* w1t = (bf16*)alloc((size_t)HIDF * CIN * 2);     // 4.7 MB
  bf16* w2t = (bf16*)alloc((size_t)OUTF * HIDF * 2);    // 1.6 MB
  bf16* wlt = (bf16*)alloc((size_t)OUTF * CIN * 2);     // 1.6 MB (~159 MB)
  float* origin = (float*)xa;
  float* g2 = (float*)xt;

  prep<<<XBLK + W1BLK + 2 * W2BLK, 256, 0, stream>>>(x, W1, W2, Wl, xt, xa,
                                                     w1t, w2t, wlt);
  // h = relu(xa @ W1 + b1) + xt
  gemm_h<<<dim3(NN / 128, HIDF / 128, NB), 256, 0, stream>>>(xa, w1t, xt, hb,
                                                             b1);
  // origin = xt @ Wl + bl  (overwrites xa slot — xa dead after gemm_h)
  gemm_f32<true><<<dim3(NN / 128, OUTF / 128, NB), 256, 0, stream>>>(
      xt, wlt, origin, bl);
  // g2 = h @ W2  (overwrites xt slot — xt dead after gemm_o)
  gemm_f32<false><<<dim3(NN / 128, OUTF / 128, NB), 256, 0, stream>>>(
      hb, w2t, g2, nullptr);
  // out = (Agg(g2)+b2) * origin, transposed to [B][OUT][N]
  stencil2<<<dim3(256, NB), 256, 0, stream>>>(g2, origin, b2, out);
}